// Round 1
// baseline (395.873 us; speedup 1.0000x reference)
//
#include <hip/hip_runtime.h>

// TimeDomainCochleagram: 4-stage cascaded gammatone biquads + relu + mean-pool(24).
// Strategy: chunk the time axis (80 chunks x 1200), each thread runs one
// (batch, channel, chunk) serially with a zero-state WARMUP of W_c samples,
// where W_c = K / (B_c * T) from the pole decay b2 = exp(-2 B T).
// K=24 -> truncated-state error ~3e-7 relative (below fp32 tolerance).
// Block = 64 lanes all on the SAME channel -> uniform warmup length (no
// divergence), wave-uniform coefficients (SGPRs). Channels launched
// longest-warmup-first so the 50 Hz critical-path blocks start at t=0.

#define T_SAMPLES 96000
#define NCH       40
#define BATCH     8
#define DOWN      24
#define NCHUNK    80
#define CHUNK_LEN (T_SAMPLES / NCHUNK)      // 1200 = 24*50, multiple of 4
#define OUT_PER_CHUNK (CHUNK_LEN / DOWN)    // 50
#define T_DOWN    (T_SAMPLES / DOWN)        // 4000
#define KDECAY    24.0f

__global__ __launch_bounds__(64)
void cochleagram_kernel(const float* __restrict__ x,
                        const float* __restrict__ fcoefs,
                        float* __restrict__ out)
{
    // channels mapped longest-warmup-first: c=39 (50 Hz, W~6000) dispatches first
    const int c = (NCH - 1) - (int)blockIdx.y;
    const int tid = (int)blockIdx.x * 64 + (int)threadIdx.x;  // 0..639
    const int b = tid / NCHUNK;
    const int chunk = tid - b * NCHUNK;

    // fcoefs row: [a0, a11, a12, a13, a14, a2(=0), 1, b1, b2, gain]
    const float* fc = fcoefs + c * 10;
    const float a0  = fc[0];
    const float gain = fc[9];
    const float n00 = a0 / gain;        // stage 0 numerators divided by gain
    const float n10 = fc[1] / gain;
    const float n11 = fc[2];
    const float n12 = fc[3];
    const float n13 = fc[4];
    const float nd1 = -fc[7];
    const float nd2 = -fc[8];

    // warmup length from pole decay: b2 = exp(-2 B T) -> B*T = -0.5 ln(b2)
    const float BT = -0.5f * logf(fc[8]);
    int W = (int)ceilf(KDECAY / BT);
    W = (W + 3) & ~3;                   // keep float4 alignment of t0

    const int chunk_start = chunk * CHUNK_LEN;
    int t0 = chunk_start - W;
    if (t0 < 0) t0 = 0;                 // early chunks: exact (true zero state)

    float s10 = 0.f, s20 = 0.f, s11 = 0.f, s21 = 0.f;
    float s12 = 0.f, s22 = 0.f, s13 = 0.f, s23 = 0.f;

    const float4* xb = reinterpret_cast<const float4*>(x + (size_t)b * T_SAMPLES);

    // One time step of the 4-stage cascade (a2 == 0 => s2' = -d2*y).
    auto step = [&](float xv) -> float {
        float y0 = fmaf(n00, xv, s10);
        s10 = fmaf(nd1, y0, fmaf(n10, xv, s20));
        s20 = nd2 * y0;
        float y1 = fmaf(a0, y0, s11);
        s11 = fmaf(nd1, y1, fmaf(n11, y0, s21));
        s21 = nd2 * y1;
        float y2 = fmaf(a0, y1, s12);
        s12 = fmaf(nd1, y2, fmaf(n12, y1, s22));
        s22 = nd2 * y2;
        float y3 = fmaf(a0, y2, s13);
        s13 = fmaf(nd1, y3, fmaf(n13, y2, s23));
        s23 = nd2 * y3;
        return y3;
    };

    // ---- warmup: state only, no output ----
    for (int t = t0; t < chunk_start; t += 4) {
        float4 xv = xb[t >> 2];
        step(xv.x); step(xv.y); step(xv.z); step(xv.w);
    }

    // ---- main: filter + relu + mean-pool(24) ----
    float* outp = out + ((size_t)b * NCH + c) * T_DOWN + chunk * OUT_PER_CHUNK;
    int t = chunk_start;
    for (int td = 0; td < OUT_PER_CHUNK; ++td) {
        float acc = 0.0f;
        #pragma unroll
        for (int q = 0; q < DOWN / 4; ++q) {
            float4 xv = xb[(t >> 2) + q];
            acc += fmaxf(step(xv.x), 0.0f);
            acc += fmaxf(step(xv.y), 0.0f);
            acc += fmaxf(step(xv.z), 0.0f);
            acc += fmaxf(step(xv.w), 0.0f);
        }
        outp[td] = acc * (1.0f / 24.0f);
        t += DOWN;
    }
}

extern "C" void kernel_launch(void* const* d_in, const int* in_sizes, int n_in,
                              void* d_out, int out_size, void* d_ws, size_t ws_size,
                              hipStream_t stream) {
    const float* x      = (const float*)d_in[0];   // (8, 96000) f32
    const float* fcoefs = (const float*)d_in[1];   // (40, 10)  f32
    float* out = (float*)d_out;                    // (8, 40, 4000) f32

    dim3 grid(BATCH * NCHUNK / 64, NCH);           // (10, 40), block = 1 wave
    cochleagram_kernel<<<grid, 64, 0, stream>>>(x, fcoefs, out);
}

// Round 3
// 212.708 us; speedup vs baseline: 1.8611x; 1.8611x over previous
//
#include <hip/hip_runtime.h>

// TimeDomainCochleagram via exact wave-parallel chunked scan.
// The 4-stage biquad cascade is linear: s' = A s + b x, A 8x8 block-lower-
// triangular (2x2 blocks), constant per channel. Per (b,c): 64 lanes each own
// a 1500-sample segment. Pass 1: run segment from zero state -> end state e_l.
// Scan: S_{l+1} = M S_l + e_l with M = A^1500 (16 block-triangular matmuls by
// square-and-multiply, computed redundantly per lane). Pass 2: re-run segment
// from exact initial state, relu + mean-pool(24). Pool windows straddle
// segment boundaries (1500 mod 24 = 12): even lane owns tail half, odd lane
// head half; combined via one shfl_down at the end.
// Loads software-pipelined in 20-sample groups (compute/group ~520cy >> L2 lat).

#define NCH 40
#define NB  8
#define TS  96000
#define DOWN 24
#define SEG 1500          // per-lane samples = TS/64
#define NG  75            // 20-sample groups per segment
#define TD  4000          // TS/DOWN

typedef float Mat[4][4][2][2];   // block-lower-triangular: only [i][j] with j<=i used

__device__ __forceinline__ void matcopy(Mat dst, const Mat src) {
    #pragma unroll
    for (int i = 0; i < 4; i++)
        #pragma unroll
        for (int j = 0; j < 4; j++) if (j <= i)
            #pragma unroll
            for (int r = 0; r < 2; r++)
                #pragma unroll
                for (int c = 0; c < 2; c++)
                    dst[i][j][r][c] = src[i][j][r][c];
}

__device__ __forceinline__ void matmul_lt(Mat C, const Mat A, const Mat B) {
    #pragma unroll
    for (int i = 0; i < 4; i++)
        #pragma unroll
        for (int j = 0; j < 4; j++) if (j <= i)
            #pragma unroll
            for (int r = 0; r < 2; r++)
                #pragma unroll
                for (int c = 0; c < 2; c++) {
                    float acc = 0.f;
                    #pragma unroll
                    for (int k = 0; k < 4; k++) if (k >= j && k <= i)
                        #pragma unroll
                        for (int q = 0; q < 2; q++)
                            acc = fmaf(A[i][k][r][q], B[k][j][q][c], acc);
                    C[i][j][r][c] = acc;
                }
}

__global__ __launch_bounds__(64, 1)
void cochlea_scan_kernel(const float* __restrict__ x,
                         const float* __restrict__ fcoefs,
                         float* __restrict__ out)
{
    const int b    = (int)blockIdx.x;
    const int c    = (int)blockIdx.y;
    const int lane = (int)threadIdx.x;

    // fcoefs row: [a0, a11, a12, a13, a14, a2(=0), 1, b1, b2, gain]
    const float* fc  = fcoefs + c * 10;
    const float a0   = fc[0];
    const float gain = fc[9];
    const float n00  = a0 / gain;
    const float n10  = fc[1] / gain;
    const float n11  = fc[2];
    const float n12  = fc[3];
    const float n13  = fc[4];
    const float nd1  = -fc[7];
    const float nd2  = -fc[8];

    float s[8];

    // one time-step of the cascade on state s (a2==0 => s2' = -d2*y)
    auto step = [&](float xv) -> float {
        float y0 = fmaf(n00, xv, s[0]);
        s[0] = fmaf(nd1, y0, fmaf(n10, xv, s[1]));
        s[1] = nd2 * y0;
        float y1 = fmaf(a0, y0, s[2]);
        s[2] = fmaf(nd1, y1, fmaf(n11, y0, s[3]));
        s[3] = nd2 * y1;
        float y2 = fmaf(a0, y1, s[4]);
        s[4] = fmaf(nd1, y2, fmaf(n12, y1, s[5]));
        s[5] = nd2 * y2;
        float y3 = fmaf(a0, y2, s[6]);
        s[6] = fmaf(nd1, y3, fmaf(n13, y2, s[7]));
        s[7] = nd2 * y3;
        return y3;
    };

    // ---- build A column-by-column by stepping unit states with x=0 ----
    Mat Ab;
    #pragma unroll
    for (int j = 0; j < 8; j++) {
        #pragma unroll
        for (int i = 0; i < 8; i++) s[i] = (i == j) ? 1.f : 0.f;
        (void)step(0.f);
        #pragma unroll
        for (int i = 0; i < 8; i++)
            if ((i >> 1) >= (j >> 1))
                Ab[i >> 1][j >> 1][i & 1][j & 1] = s[i];
    }

    // ---- M = A^1500 by square-and-multiply (1500 = 0b10111011100) ----
    Mat R, Tm;
    matcopy(R, Ab);
    const int bits[10] = {0, 1, 1, 1, 0, 1, 1, 1, 0, 0};  // after MSB
    #pragma unroll
    for (int t = 0; t < 10; t++) {
        matmul_lt(Tm, R, R);
        if (bits[t]) matmul_lt(R, Tm, Ab);
        else         matcopy(R, Tm);
    }

    // ---- load pipeline helpers (20 samples = 5 float4 per group) ----
    const float4* xb4 = reinterpret_cast<const float4*>(x + (size_t)b * TS) + lane * (SEG / 4);
    float4 bufA[5], bufB[5];
    auto loadg = [&](float4 (&buf)[5], int g) {
        #pragma unroll
        for (int q = 0; q < 5; q++) buf[q] = xb4[g * 5 + q];
    };

    // ---- pass 1: zero-state local run, keep end state ----
    #pragma unroll
    for (int i = 0; i < 8; i++) s[i] = 0.f;
    auto comp1 = [&](const float4 (&buf)[5]) {
        #pragma unroll
        for (int q = 0; q < 5; q++) {
            step(buf[q].x); step(buf[q].y); step(buf[q].z); step(buf[q].w);
        }
    };
    loadg(bufA, 0);
    for (int p = 0; p < 37; p++) {
        loadg(bufB, 2 * p + 1);
        comp1(bufA);
        loadg(bufA, 2 * p + 2);
        comp1(bufB);
    }
    comp1(bufA);  // group 74

    // ---- share end states, serial-redundant affine scan across lanes ----
    __shared__ float elds[64][8];
    #pragma unroll
    for (int i = 0; i < 8; i++) elds[lane][i] = s[i];
    __syncthreads();

    float run[8], init[8];
    #pragma unroll
    for (int i = 0; i < 8; i++) { run[i] = 0.f; init[i] = 0.f; }
    for (int j = 0; j < 63; j++) {
        float e[8];
        #pragma unroll
        for (int i = 0; i < 8; i++) e[i] = elds[j][i];
        float nr[8];
        #pragma unroll
        for (int rb = 0; rb < 4; rb++)
            #pragma unroll
            for (int ri = 0; ri < 2; ri++) {
                float acc = e[2 * rb + ri];
                #pragma unroll
                for (int cb = 0; cb < 4; cb++) if (cb <= rb)
                    #pragma unroll
                    for (int ci = 0; ci < 2; ci++)
                        acc = fmaf(R[rb][cb][ri][ci], run[2 * cb + ci], acc);
                nr[2 * rb + ri] = acc;
            }
        #pragma unroll
        for (int i = 0; i < 8; i++) run[i] = nr[i];
        bool hit = (lane == j + 1);
        #pragma unroll
        for (int i = 0; i < 8; i++) init[i] = hit ? run[i] : init[i];
    }

    // ---- pass 2: exact initial state, relu + mean-pool(24) ----
    #pragma unroll
    for (int i = 0; i < 8; i++) s[i] = init[i];

    float acc = 0.f;
    float head = 0.f;
    const int odd = lane & 1;
    int cnt = odd ? 12 : 0;                       // odd lanes start mid-window
    int w = (lane * SEG - (odd ? 12 : 0)) / DOWN; // first window index touched
    bool first_skip = odd;                        // odd lane's first reset = head partial
    float* outp = out + ((size_t)b * NCH + c) * TD;

    auto emit = [&](float y) {
        acc += fmaxf(y, 0.f);
        if (++cnt == DOWN) {
            if (first_skip) { head = acc; first_skip = false; }
            else            { outp[w] = acc * (1.f / 24.f); }
            w++; acc = 0.f; cnt = 0;
        }
    };
    auto comp2 = [&](const float4 (&buf)[5]) {
        #pragma unroll
        for (int q = 0; q < 5; q++) {
            emit(step(buf[q].x)); emit(step(buf[q].y));
            emit(step(buf[q].z)); emit(step(buf[q].w));
        }
    };
    loadg(bufA, 0);
    for (int p = 0; p < 37; p++) {
        loadg(bufB, 2 * p + 1);
        comp2(bufA);
        loadg(bufA, 2 * p + 2);
        comp2(bufB);
    }
    comp2(bufA);  // group 74

    // straddled window: even lane's 12-sample tail + odd lane's 12-sample head
    float head_next = __shfl_down(head, 1, 64);
    if (!odd) {
        outp[w] = (acc + head_next) * (1.f / 24.f);
    }
}

extern "C" void kernel_launch(void* const* d_in, const int* in_sizes, int n_in,
                              void* d_out, int out_size, void* d_ws, size_t ws_size,
                              hipStream_t stream) {
    const float* x      = (const float*)d_in[0];   // (8, 96000) f32
    const float* fcoefs = (const float*)d_in[1];   // (40, 10)  f32
    float* out = (float*)d_out;                    // (8, 40, 4000) f32

    dim3 grid(NB, NCH);        // 320 blocks, one wave each
    cochlea_scan_kernel<<<grid, 64, 0, stream>>>(x, fcoefs, out);
}

// Round 7
// 122.205 us; speedup vs baseline: 3.2394x; 1.7406x over previous
//
#include <hip/hip_runtime.h>

// TimeDomainCochleagram: exact chunked scan, 256 segments x 375 samples.
// The 4-stage biquad cascade is linear: s' = A s + b x (A: 8x8, 2x2-block
// lower-triangular, per-channel constant).
//   setup (1 block, fp64): per channel, Mk = A^(375*2^k), k=0..7 -> d_ws.
//   main (block = (b,c), 256 threads = 4 waves):
//     pass 1: each lane runs its 375-sample segment from zero state -> e_g.
//     scan:   dp Kogge-Stone over 256 end-states (8 levels, LDS ping-pong):
//             t_g <- t_g + Mk * t_{g-2^k}; init state = t_{g-1} (exclusive).
//             fp64 scan+matrices: round-5's fp32 scan failed accuracy (1.03e-2
//             vs 8.05e-3 thr); recombination rounding on ~1e2-magnitude states
//             over 127 hops was the suspect. dp makes recombination exact.
//     pass 2: re-run segment from exact init, relu + mean-pool(24).
//             375 = 15 mod 24 -> window boundaries land on 3-sample marks;
//             boundary check once per 3 samples: (jj+1+5g) % 8 == 0.
//             Straddled windows: head via shfl_down; lanes g%8==7 have zero
//             tail; no straddle crosses a wave (375*64 % 24 == 0).

#define NCH  40
#define NB   8
#define TS   96000
#define DOWN 24
#define NSEG 256
#define SEG  375
#define TD   4000
#define NLVL 8
#define INV24 (1.0f/24.0f)

typedef double DMat[4][4][2][2];   // 2x2 blocks; only j<=i used

__device__ __forceinline__ void dmatcopy(DMat dst, const DMat src) {
    #pragma unroll
    for (int i = 0; i < 4; i++)
        #pragma unroll
        for (int j = 0; j < 4; j++) if (j <= i)
            #pragma unroll
            for (int r = 0; r < 2; r++)
                #pragma unroll
                for (int c = 0; c < 2; c++)
                    dst[i][j][r][c] = src[i][j][r][c];
}

__device__ __forceinline__ void dmatmul(DMat C, const DMat A, const DMat B) {
    #pragma unroll
    for (int i = 0; i < 4; i++)
        #pragma unroll
        for (int j = 0; j < 4; j++) if (j <= i)
            #pragma unroll
            for (int r = 0; r < 2; r++)
                #pragma unroll
                for (int c = 0; c < 2; c++) {
                    double acc = 0.0;
                    #pragma unroll
                    for (int k = 0; k < 4; k++) if (k >= j && k <= i)
                        #pragma unroll
                        for (int q = 0; q < 2; q++)
                            acc += A[i][k][r][q] * B[k][j][q][c];
                    C[i][j][r][c] = acc;
                }
}

// ---------- setup: Mk = A^(375*2^k), k=0..7, fp64, 40 doubles per matrix ----------
__global__ __launch_bounds__(64)
void cochlea_setup(const float* __restrict__ fcoefs, double* __restrict__ ws)
{
    const int c = (int)threadIdx.x;
    if (c >= NCH) return;
    const float* fc = fcoefs + c * 10;
    const double a0  = (double)fc[0];
    const double n11 = (double)fc[2], n12 = (double)fc[3], n13 = (double)fc[4];
    const double nd1 = -(double)fc[7], nd2 = -(double)fc[8];

    double s[8];
    auto step0 = [&]() {     // one cascade step, x = 0, fp64
        double y0 = s[0];
        s[0] = nd1 * y0 + s[1];
        s[1] = nd2 * y0;
        double y1 = a0 * y0 + s[2];
        s[2] = nd1 * y1 + (n11 * y0 + s[3]);
        s[3] = nd2 * y1;
        double y2 = a0 * y1 + s[4];
        s[4] = nd1 * y2 + (n12 * y1 + s[5]);
        s[5] = nd2 * y2;
        double y3 = a0 * y2 + s[6];
        s[6] = nd1 * y3 + (n13 * y2 + s[7]);
        s[7] = nd2 * y3;
    };

    DMat A, P, T;
    #pragma unroll
    for (int j = 0; j < 8; j++) {
        #pragma unroll
        for (int i = 0; i < 8; i++) s[i] = (i == j) ? 1.0 : 0.0;
        step0();
        #pragma unroll
        for (int i = 0; i < 8; i++)
            if ((i >> 1) >= (j >> 1))
                A[i >> 1][j >> 1][i & 1][j & 1] = s[i];
    }

    // P = A^375; 375 = 0b101110111 -> tail bits after MSB: 0,1,1,1,0,1,1,1
    dmatcopy(P, A);
    const int bits[8] = {0, 1, 1, 1, 0, 1, 1, 1};
    #pragma unroll
    for (int t = 0; t < 8; t++) {
        dmatmul(T, P, P);
        if (bits[t]) dmatmul(P, T, A);
        else         dmatcopy(P, T);
    }

    // store levels: Mk = P^(2^k); traversal (rb, cb<=rb, ri, ci),
    // linear idx = (rb*(rb+1)/2 + cb)*4 + ri*2 + ci  (matches main kernel)
    double* o = ws + (size_t)c * (NLVL * 40);
    for (int k = 0; k < NLVL; k++) {
        #pragma unroll
        for (int rb = 0; rb < 4; rb++)
            #pragma unroll
            for (int cb = 0; cb < 4; cb++) if (cb <= rb)
                #pragma unroll
                for (int ri = 0; ri < 2; ri++)
                    #pragma unroll
                    for (int ci = 0; ci < 2; ci++)
                        o[k * 40 + (rb * (rb + 1) / 2 + cb) * 4 + ri * 2 + ci] = P[rb][cb][ri][ci];
        if (k < NLVL - 1) { dmatmul(T, P, P); dmatcopy(P, T); }
    }
}

// ---------- main: pass1 -> dp Kogge-Stone scan -> pass2 ----------
__global__ __launch_bounds__(256, 1)
void cochlea_main(const float* __restrict__ x,
                  const float* __restrict__ fcoefs,
                  const double* __restrict__ ws,
                  float* __restrict__ out)
{
    const int b = (int)blockIdx.x;
    const int c = (int)blockIdx.y;
    const int g = (int)threadIdx.x;        // segment index 0..255

    const float* fc  = fcoefs + c * 10;
    const float a0   = fc[0];
    const float gain = fc[9];
    const float n00  = a0 / gain;
    const float n10  = fc[1] / gain;
    const float n11  = fc[2];
    const float n12  = fc[3];
    const float n13  = fc[4];
    const float nd1  = -fc[7];
    const float nd2  = -fc[8];

    float s[8];
    auto step = [&](float xv) -> float {
        float y0 = fmaf(n00, xv, s[0]);
        s[0] = fmaf(nd1, y0, fmaf(n10, xv, s[1]));
        s[1] = nd2 * y0;
        float y1 = fmaf(a0, y0, s[2]);
        s[2] = fmaf(nd1, y1, fmaf(n11, y0, s[3]));
        s[3] = nd2 * y1;
        float y2 = fmaf(a0, y1, s[4]);
        s[4] = fmaf(nd1, y2, fmaf(n12, y1, s[5]));
        s[5] = nd2 * y2;
        float y3 = fmaf(a0, y2, s[6]);
        s[6] = fmaf(nd1, y3, fmaf(n13, y2, s[7]));
        s[7] = nd2 * y3;
        return y3;
    };

    // segment stream: 25 macro-groups of 15 samples (5 float3), double-buffered
    const float3* xb3 = reinterpret_cast<const float3*>(x + (size_t)b * TS + (size_t)g * SEG);
    float3 bA[5], bB[5];
    auto loadg = [&](float3 (&bf)[5], int m) {
        #pragma unroll
        for (int q = 0; q < 5; q++) bf[q] = xb3[m * 5 + q];
    };

    // ---- pass 1: zero state -> end state ----
    #pragma unroll
    for (int i = 0; i < 8; i++) s[i] = 0.f;
    auto c1 = [&](const float3 (&bf)[5]) {
        #pragma unroll
        for (int q = 0; q < 5; q++) { step(bf[q].x); step(bf[q].y); step(bf[q].z); }
    };
    loadg(bA, 0);
    for (int p = 0; p < 12; p++) {
        loadg(bB, 2 * p + 1);
        c1(bA);
        loadg(bA, 2 * p + 2);
        c1(bB);
    }
    c1(bA);   // macro-group 24

    // ---- dp Kogge-Stone inclusive scan over 256 end states ----
    __shared__ double tk[2][NSEG][9];   // pad row to 9 dbl (72B) vs bank aliasing
    double td[8];
    #pragma unroll
    for (int i = 0; i < 8; i++) td[i] = (double)s[i];
    int cur = 0;
    #pragma unroll
    for (int i = 0; i < 8; i++) tk[0][g][i] = td[i];
    __syncthreads();

    const double* wsc = ws + (size_t)c * (NLVL * 40);
    for (int k = 0; k < NLVL; k++) {
        double M[40];
        #pragma unroll
        for (int q = 0; q < 40; q++) M[q] = wsc[k * 40 + q];
        double nt[8];
        const int src = g - (1 << k);
        if (src >= 0) {
            double pr[8];
            #pragma unroll
            for (int i = 0; i < 8; i++) pr[i] = tk[cur][src][i];
            #pragma unroll
            for (int rb = 0; rb < 4; rb++)
                #pragma unroll
                for (int ri = 0; ri < 2; ri++) {
                    double acc = td[2 * rb + ri];
                    #pragma unroll
                    for (int cb = 0; cb < 4; cb++) if (cb <= rb)
                        #pragma unroll
                        for (int ci = 0; ci < 2; ci++)
                            acc += M[(rb * (rb + 1) / 2 + cb) * 4 + ri * 2 + ci] * pr[2 * cb + ci];
                    nt[2 * rb + ri] = acc;
                }
        } else {
            #pragma unroll
            for (int i = 0; i < 8; i++) nt[i] = td[i];
        }
        // reads hit tk[cur], writes go to tk[cur^1]: no hazard; one barrier/level
        #pragma unroll
        for (int i = 0; i < 8; i++) tk[cur ^ 1][g][i] = nt[i];
        __syncthreads();
        #pragma unroll
        for (int i = 0; i < 8; i++) td[i] = nt[i];
        cur ^= 1;
    }

    // exclusive: init for segment g = inclusive[g-1]; segment 0 = zero state
    #pragma unroll
    for (int i = 0; i < 8; i++)
        s[i] = (g == 0) ? 0.f : (float)tk[cur][g - 1][i];

    // ---- pass 2: exact init, relu + mean-pool(24), 3-sample boundary logic ----
    const int g8      = g & 7;
    const int offset  = (15 * g8) % 24;          // segment start mod 24
    const int r       = (24 - offset) % 24;      // head length (samples)
    const bool hashead = (offset != 0);
    const int w0      = (SEG * g + r) / 24;      // first own full-window index
    const int ph      = (1 + 5 * g8) & 7;        // boundary iff (jj + ph) % 8 == 0
    float* outp = out + ((size_t)b * NCH + c) * TD;

    float acc = 0.f, head = 0.f;
    int kb = 0;

    auto c2 = [&](const float3 (&bf)[5], int m) {
        #pragma unroll
        for (int q = 0; q < 5; q++) {
            float3 v = bf[q];
            acc += fmaxf(step(v.x), 0.f);
            acc += fmaxf(step(v.y), 0.f);
            acc += fmaxf(step(v.z), 0.f);
            int jj = m * 5 + q;
            if (((jj + ph) & 7) == 0) {          // window boundary for this lane
                bool ishead = hashead && (kb == 0);
                if (ishead) head = acc;
                else        outp[w0 + kb - (hashead ? 1 : 0)] = acc * INV24;
                kb++;
                acc = 0.f;
            }
        }
    };
    loadg(bA, 0);
    for (int p = 0; p < 12; p++) {
        loadg(bB, 2 * p + 1);
        c2(bA, 2 * p);
        loadg(bA, 2 * p + 2);
        c2(bB, 2 * p + 1);
    }
    c2(bA, 24);

    // straddled window: my tail + right neighbor's head.
    // Lanes g%8==7 have zero tail (375*(g+1) % 24 == 0) -> no straddle; this
    // includes g=63,127,191,255, so shfl never needs to cross a wave boundary.
    float hnext = __shfl_down(head, 1, 64);      // executed by all lanes
    if (g8 != 7)
        outp[w0 + kb - (hashead ? 1 : 0)] = (acc + hnext) * INV24;
}

extern "C" void kernel_launch(void* const* d_in, const int* in_sizes, int n_in,
                              void* d_out, int out_size, void* d_ws, size_t ws_size,
                              hipStream_t stream) {
    const float* x      = (const float*)d_in[0];   // (8, 96000) f32
    const float* fcoefs = (const float*)d_in[1];   // (40, 10)  f32
    float* out = (float*)d_out;                    // (8, 40, 4000) f32
    double* ws = (double*)d_ws;                    // 40*8*40 doubles = 100 KB

    cochlea_setup<<<1, 64, 0, stream>>>(fcoefs, ws);
    dim3 grid(NB, NCH);                            // 320 blocks x 4 waves
    cochlea_main<<<grid, 256, 0, stream>>>(x, fcoefs, ws, out);
}